// Round 5
// baseline (558.599 us; speedup 1.0000x reference)
//
#include <hip/hip_runtime.h>
#include <hip/hip_bf16.h>
#include <math.h>

#define B_    16
#define L_    2048
#define H_    512
#define NT_   8
#define OUT_  1032
#define KPAD_ 1056
#define HEAD_ 256
#define CH_   16
#define CL_   (L_/CH_)   // 128

// k5 A-LDS geometry: 32 rows, 136 chunks of 16B (2176B row), XOR-swizzled
#define ACH_  136
#define ASTR_ (ACH_*8)   // shorts per row = 1088

typedef short bf16x8 __attribute__((ext_vector_type(8)));
typedef float f32x4  __attribute__((ext_vector_type(4)));

__device__ __forceinline__ float b2f(unsigned short u) {
    union { unsigned int u32; float f; } v; v.u32 = ((unsigned int)u) << 16; return v.f;
}
__device__ __forceinline__ unsigned short f2b(float f) {
    __hip_bfloat16 h = __float2bfloat16(f);
    return *reinterpret_cast<unsigned short*>(&h);
}
__device__ __forceinline__ float sigmoid_f(float x) {
    return 1.f / (1.f + exp2f(-1.44269504f * x));
}
__device__ __forceinline__ float tanh_f(float x) {
    float e = exp2f(2.88539008f * x);
    return 1.f - 2.f / (e + 1.f);
}
__device__ __forceinline__ float gelu_f(float g) {
    float u  = 0.70710678118654752f * g;
    float ax = fabsf(u);
    float t  = 1.f / (1.f + 0.3275911f * ax);
    float poly = ((((1.061405429f*t - 1.453152027f)*t + 1.421413741f)*t
                   - 0.284496736f)*t + 0.254829592f)*t;
    float e  = exp2f(-1.44269504f * ax * ax);
    float er = 1.f - poly * e;
    er = (u < 0.f) ? -er : er;
    return 0.5f * g * (1.f + er);
}

// ---------------------------------------------------------------------------
// kT: transpose + f32->bf16. in f32 [R][C] -> out bf16 [C][RP], zero r>=R.
// ---------------------------------------------------------------------------
__global__ __launch_bounds__(256) void kT(const float* __restrict__ in,
                                          unsigned short* __restrict__ out,
                                          int R, int C, int RP)
{
    __shared__ float tile[32][33];
    int c0 = blockIdx.x * 32, r0 = blockIdx.y * 32;
    int tx = threadIdx.x & 31, ty = threadIdx.x >> 5;
    #pragma unroll
    for (int j = 0; j < 32; j += 8) {
        int r = r0 + ty + j, c = c0 + tx;
        tile[ty + j][tx] = (r < R && c < C) ? in[(size_t)r*C + c] : 0.f;
    }
    __syncthreads();
    #pragma unroll
    for (int j = 0; j < 32; j += 8) {
        int c = c0 + ty + j, r = r0 + tx;
        if (c < C && r < RP) out[(size_t)c*RP + r] = f2b(tile[tx][ty + j]);
    }
}

// ---------------------------------------------------------------------------
// kP: pack Wg1 (f32 [OUT_][256]) into MFMA B-fragment chunks:
// P[kb*1024 + c*4 + kg] = bf16 Wg1[kb*32+kg*8 .. +8][c]  (zero for k>=OUT_)
// ---------------------------------------------------------------------------
__global__ __launch_bounds__(256) void kP(const float* __restrict__ Wg1,
                                          uint4* __restrict__ P)
{
    int idx = blockIdx.x*256 + threadIdx.x;
    if (idx >= 33*1024) return;
    int kb = idx >> 10;
    int rem = idx & 1023;
    int c  = rem >> 2;
    int kg = rem & 3;
    int k0 = kb*32 + kg*8;
    unsigned short o[8];
    #pragma unroll
    for (int j = 0; j < 8; j++) {
        int k = k0 + j;
        o[j] = (k < OUT_) ? f2b(Wg1[(size_t)k*HEAD_ + c]) : (unsigned short)0;
    }
    P[idx] = *(const uint4*)o;
}

// ---------------------------------------------------------------------------
// K1: wave-per-row. t_enc MLP (all lanes redundantly; weights -> s_loads),
// then 8 cols/lane of inp = xc @ Wp + bp, uint4 stores. 4 rows per block.
// ---------------------------------------------------------------------------
__global__ __launch_bounds__(256) void k1_tenc_inp(
    const float* __restrict__ x, const float* __restrict__ t,
    const float* __restrict__ Wt1, const float* __restrict__ bt1,
    const float* __restrict__ Wt2, const float* __restrict__ bt2,
    const float* __restrict__ Wpf, const float* __restrict__ bpf,
    const float* __restrict__ Wpb, const float* __restrict__ bpb,
    float* __restrict__ t_enc,
    unsigned short* __restrict__ inp_f, unsigned short* __restrict__ inp_b)
{
    int wv = threadIdx.x >> 6, lane = threadIdx.x & 63;
    size_t row = (size_t)blockIdx.x*4 + wv;
    float tv = t[row];
    float r1[NT_], te[NT_];
    #pragma unroll
    for (int k = 0; k < NT_; k++) r1[k] = fmaxf(tv*Wt1[k] + bt1[k], 0.f);
    #pragma unroll
    for (int j = 0; j < NT_; j++) {
        float a = bt2[j];
        #pragma unroll
        for (int k = 0; k < NT_; k++) a = fmaf(r1[k], Wt2[k*NT_+j], a);
        te[j] = a;
    }
    if (lane < NT_) t_enc[row*NT_ + lane] = te[lane];
    float x0 = x[row*2+0], x1 = x[row*2+1];
    int c0 = lane*8;
    float af[8], ab[8];
    #pragma unroll
    for (int j = 0; j < 8; j++) {
        int c = c0 + j;
        af[j] = fmaf(x0, Wpf[c], fmaf(x1, Wpf[H_+c], bpf[c]));
        ab[j] = fmaf(x0, Wpb[c], fmaf(x1, Wpb[H_+c], bpb[c]));
    }
    #pragma unroll
    for (int k = 0; k < NT_; k++) {
        #pragma unroll
        for (int j = 0; j < 8; j++) {
            af[j] = fmaf(te[k], Wpf[(2+k)*H_+c0+j], af[j]);
            ab[j] = fmaf(te[k], Wpb[(2+k)*H_+c0+j], ab[j]);
        }
    }
    unsigned short of[8], ob[8];
    #pragma unroll
    for (int j = 0; j < 8; j++) { of[j] = f2b(af[j]); ob[j] = f2b(ab[j]); }
    *(uint4*)&inp_f[row*H_ + c0] = *(const uint4*)of;
    *(uint4*)&inp_b[row*H_ + c0] = *(const uint4*)ob;
}

// ---------------------------------------------------------------------------
// K3 (MFMA): ab = pack(1-sig(inp@Wz+bz), sig*tanh(inp@Wh+bh)).
// Tile 128x64(x2 matrices), BK=64, XOR-swizzled tight LDS (128B rows,
// chunk ^= row&7). 4 waves 2x2; per wave 64x32 per matrix.
// ---------------------------------------------------------------------------
__global__ __launch_bounds__(256) void k3_mfma(
    const unsigned short* __restrict__ inp,   // [M][512] bf16
    const unsigned short* __restrict__ WzT,   // [512][512] bf16, [n][k]
    const unsigned short* __restrict__ WhT,
    const float* __restrict__ bz, const float* __restrict__ bh,
    unsigned int* __restrict__ ab_out)
{
    __shared__ __align__(16) unsigned short As[128*64];  // 16KB
    __shared__ __align__(16) unsigned short Zs[64*64];   // 8KB
    __shared__ __align__(16) unsigned short Hs[64*64];   // 8KB
    int tid = threadIdx.x;
    int lane = tid & 63, w = tid >> 6;
    int wm = w >> 1, wn = w & 1;
    int row0 = blockIdx.x * 128;
    int n0   = blockIdx.y * 64;
    int kg = lane >> 4, lr = lane & 15;

    f32x4 accz[4][2], acch[4][2];
    #pragma unroll
    for (int m = 0; m < 4; m++)
        #pragma unroll
        for (int n = 0; n < 2; n++) {
            accz[m][n] = (f32x4){0.f,0.f,0.f,0.f};
            acch[m][n] = (f32x4){0.f,0.f,0.f,0.f};
        }

    int arow = tid & 127, ahalf = tid >> 7;     // A: 128 rows x 2 halves
    int bu = tid & 127;
    int brow = bu & 63, bhalf = bu >> 6;        // B: 64 rows x 2 halves x {Z,H}
    const unsigned short* WT = (tid < 128) ? WzT : WhT;
    unsigned short* BS = (tid < 128) ? Zs : Hs;

    for (int k0 = 0; k0 < H_; k0 += 64) {
        const uint4* ga = (const uint4*)&inp[(size_t)(row0+arow)*H_ + k0 + ahalf*32];
        uint4 va[4];
        #pragma unroll
        for (int j = 0; j < 4; j++) va[j] = ga[j];
        const uint4* gb = (const uint4*)&WT[(size_t)(n0+brow)*H_ + k0 + bhalf*32];
        uint4 vb[4];
        #pragma unroll
        for (int j = 0; j < 4; j++) vb[j] = gb[j];
        __syncthreads();
        #pragma unroll
        for (int j = 0; j < 4; j++) {
            int cha = (ahalf*4 + j) ^ (arow & 7);
            *(uint4*)&As[arow*64 + cha*8] = va[j];
            int chb = (bhalf*4 + j) ^ (brow & 7);
            *(uint4*)&BS[brow*64 + chb*8] = vb[j];
        }
        __syncthreads();
        #pragma unroll
        for (int ks = 0; ks < 2; ks++) {
            bf16x8 af[4], zf[2], hf[2];
            #pragma unroll
            for (int m = 0; m < 4; m++) {
                int r = wm*64 + m*16 + lr;
                af[m] = *(const bf16x8*)&As[r*64 + (((ks*4+kg) ^ (r&7))*8)];
            }
            #pragma unroll
            for (int n = 0; n < 2; n++) {
                int c = wn*32 + n*16 + lr;
                zf[n] = *(const bf16x8*)&Zs[c*64 + (((ks*4+kg) ^ (c&7))*8)];
                hf[n] = *(const bf16x8*)&Hs[c*64 + (((ks*4+kg) ^ (c&7))*8)];
            }
            #pragma unroll
            for (int m = 0; m < 4; m++)
                #pragma unroll
                for (int n = 0; n < 2; n++) {
                    accz[m][n] = __builtin_amdgcn_mfma_f32_16x16x32_bf16(af[m], zf[n], accz[m][n], 0, 0, 0);
                    acch[m][n] = __builtin_amdgcn_mfma_f32_16x16x32_bf16(af[m], hf[n], acch[m][n], 0, 0, 0);
                }
        }
    }

    #pragma unroll
    for (int m = 0; m < 4; m++)
        #pragma unroll
        for (int n = 0; n < 2; n++) {
            int colg = n0 + wn*32 + n*16 + lr;
            float bzv = bz[colg], bhv = bh[colg];
            #pragma unroll
            for (int r = 0; r < 4; r++) {
                int rowg = row0 + wm*64 + m*16 + kg*4 + r;
                float zg = sigmoid_f(accz[m][n][r] + bzv);
                float a = 1.f - zg;
                float b = zg * tanh_f(acch[m][n][r] + bhv);
                ab_out[(size_t)rowg*H_ + colg] =
                    (unsigned int)f2b(a) | ((unsigned int)f2b(b) << 16);
            }
        }
}

// ---------------------------------------------------------------------------
// K4a: chunked scan pass A. In-place: read gate pack(a,b), write pack(S,PP).
// ---------------------------------------------------------------------------
__global__ __launch_bounds__(256) void k4a(
    unsigned int* __restrict__ ABF, unsigned int* __restrict__ ABB,
    float* __restrict__ Scar, float* __restrict__ Pcar, int nb)
{
    int g = blockIdx.x*256 + threadIdx.x;
    int col   = g & (H_-1);
    int chunk = (g >> 9) & (CH_-1);
    int rest  = g >> 13;
    int bb    = rest % nb;
    int dir   = rest / nb;
    unsigned int* AB = dir ? ABB : ABF;
    size_t base = (size_t)bb * L_ * H_ + col;
    float h = 0.f, pp = 1.f;
    if (dir == 0) {
        int lo = chunk * CL_;
        for (int p = 0; p < CL_; p += 8) {
            unsigned int v[8];
            #pragma unroll
            for (int j = 0; j < 8; j++) v[j] = AB[base + (size_t)(lo+p+j)*H_];
            #pragma unroll
            for (int j = 0; j < 8; j++) {
                size_t idx = base + (size_t)(lo+p+j)*H_;
                float av = b2f((unsigned short)(v[j] & 0xffffu));
                float bv = b2f((unsigned short)(v[j] >> 16));
                AB[idx] = (unsigned int)f2b(h) | ((unsigned int)f2b(pp) << 16);
                h = fmaf(av, h, bv);
                pp *= av;
            }
        }
    } else {
        int hi = chunk * CL_ + CL_ - 1;
        for (int p = 0; p < CL_; p += 8) {
            unsigned int v[8];
            #pragma unroll
            for (int j = 0; j < 8; j++) v[j] = AB[base + (size_t)(hi-p-j)*H_];
            #pragma unroll
            for (int j = 0; j < 8; j++) {
                size_t idx = base + (size_t)(hi-p-j)*H_;
                float av = b2f((unsigned short)(v[j] & 0xffffu));
                float bv = b2f((unsigned short)(v[j] >> 16));
                AB[idx] = (unsigned int)f2b(h) | ((unsigned int)f2b(pp) << 16);
                h = fmaf(av, h, bv);
                pp *= av;
            }
        }
    }
    int ci = ((dir*nb + bb)*CH_ + chunk)*H_ + col;
    Scar[ci] = h; Pcar[ci] = pp;
}

// K4b: chain carries across chunks.
__global__ __launch_bounds__(256) void k4b(
    const float* __restrict__ Scar, const float* __restrict__ Pcar,
    float* __restrict__ Hstart, int nb)
{
    int g = blockIdx.x*256 + threadIdx.x;
    int col  = g & (H_-1);
    int rest = g >> 9;
    int bb   = rest % nb;
    int dir  = rest / nb;
    int baseci = (dir*nb + bb)*CH_;
    float h = 0.f;
    if (dir == 0) {
        for (int c = 0; c < CH_; c++) {
            int ci = (baseci + c)*H_ + col;
            Hstart[ci] = h;
            h = Scar[ci] + Pcar[ci]*h;
        }
    } else {
        for (int c = CH_-1; c >= 0; c--) {
            int ci = (baseci + c)*H_ + col;
            Hstart[ci] = h;
            h = Scar[ci] + Pcar[ci]*h;
        }
    }
}

// ---------------------------------------------------------------------------
// K5 fused: (h = S + PP*h0) + LN(1032) + affine + time_scale -> XOR-swizzled
// LDS A [32][136 chunks], then barrier-free head GEMM with fragment-packed
// B loads (fully coalesced), gelu*Wg2 + shfl row-reduce epilogue.
// ---------------------------------------------------------------------------
__global__ __launch_bounds__(256) void k5_fused(
    const unsigned int* __restrict__ SPF, const unsigned int* __restrict__ SPB,
    const float* __restrict__ Hstart,
    const float* __restrict__ tenc,
    const float* __restrict__ ln_g, const float* __restrict__ ln_b,
    const float* __restrict__ tsp,
    const uint4* __restrict__ P,              // packed Wg1 fragments
    const float* __restrict__ bg1, const float* __restrict__ Wg2,
    const float* __restrict__ bg2,
    float* __restrict__ out, int nb)
{
    __shared__ __align__(16) unsigned short A[32*ASTR_];   // 68KB
    __shared__ float red[4][32];
    int tid = threadIdx.x, lane = tid & 63, wv = tid >> 6;
    int kg = lane >> 4, lr = lane & 15;
    int row0 = blockIdx.x * 32;
    float ts = tsp[0];

    // per-block chunk carries (all 32 rows share bb & chunk)
    int bb    = row0 >> 11;          // / L_
    int chunk = (row0 & (L_-1)) >> 7;
    int cif = ((bb)*CH_ + chunk)*H_;
    int cib = ((nb + bb)*CH_ + chunk)*H_;
    int c0 = lane*8;
    float4 hfa = *(const float4*)&Hstart[cif + c0];
    float4 hfb = *(const float4*)&Hstart[cif + c0 + 4];
    float4 hba = *(const float4*)&Hstart[cib + c0];
    float4 hbb = *(const float4*)&Hstart[cib + c0 + 4];
    float h0f[8] = {hfa.x,hfa.y,hfa.z,hfa.w,hfb.x,hfb.y,hfb.z,hfb.w};
    float h0b[8] = {hba.x,hba.y,hba.z,hba.w,hbb.x,hbb.y,hbb.z,hbb.w};

    float gf[8], bf_[8], gb_[8], bb_[8];
    #pragma unroll
    for (int j = 0; j < 8; j++) {
        gf[j]  = ln_g[c0+j];     bf_[j] = ln_b[c0+j];
        gb_[j] = ln_g[H_+c0+j];  bb_[j] = ln_b[H_+c0+j];
    }
    float gt = 0.f, bt = 0.f;
    if (lane < NT_) { gt = ln_g[2*H_+lane]; bt = ln_b[2*H_+lane]; }

    #pragma unroll
    for (int i = 0; i < 8; i++) {
        int r = wv*8 + i;
        size_t row = (size_t)row0 + r;
        const uint4* pf = (const uint4*)&SPF[row*H_ + c0];
        uint4 f0 = pf[0], f1 = pf[1];
        const uint4* pb = (const uint4*)&SPB[row*H_ + c0];
        uint4 b0 = pb[0], b1 = pb[1];
        const unsigned int* fw = (const unsigned int*)&f0;   // f0,f1 adjacent
        const unsigned int* bw = (const unsigned int*)&b0;
        unsigned int fwv[8] = {f0.x,f0.y,f0.z,f0.w,f1.x,f1.y,f1.z,f1.w};
        unsigned int bwv[8] = {b0.x,b0.y,b0.z,b0.w,b1.x,b1.y,b1.z,b1.w};
        (void)fw; (void)bw;
        float fv[8], bv[8];
        float S = 0.f, Q = 0.f;
        #pragma unroll
        for (int j = 0; j < 8; j++) {
            fv[j] = fmaf(b2f((unsigned short)(fwv[j] >> 16)), h0f[j],
                         b2f((unsigned short)(fwv[j] & 0xffffu)));
            S += fv[j]; Q += fv[j]*fv[j];
            bv[j] = fmaf(b2f((unsigned short)(bwv[j] >> 16)), h0b[j],
                         b2f((unsigned short)(bwv[j] & 0xffffu)));
            S += bv[j]; Q += bv[j]*bv[j];
        }
        float tv = 0.f;
        if (lane < NT_) { tv = tenc[row*NT_ + lane]; S += tv; Q += tv*tv; }
        #pragma unroll
        for (int off = 32; off > 0; off >>= 1) {
            S += __shfl_xor(S, off, 64);
            Q += __shfl_xor(Q, off, 64);
        }
        float mu = S * (1.f/1032.f);
        float rs = rsqrtf(Q * (1.f/1032.f) - mu*mu + 1e-5f);
        int key = r & 7;
        unsigned short o[8];
        #pragma unroll
        for (int j = 0; j < 8; j++) o[j] = f2b((fv[j]-mu)*rs*gf[j] + bf_[j]);
        *(uint4*)&A[r*ASTR_ + ((lane ^ key)*8)] = *(const uint4*)o;
        #pragma unroll
        for (int j = 0; j < 8; j++) o[j] = f2b((bv[j]-mu)*rs*gb_[j] + bb_[j]);
        *(uint4*)&A[r*ASTR_ + (((64+lane) ^ key)*8)] = *(const uint4*)o;
        if (lane < NT_) {
            // col 1024+lane -> chunk 128, short offset lane
            A[r*ASTR_ + ((128 ^ key)*8) + lane] =
                f2b(((tv-mu)*rs*gt + bt) * ts);
        } else if (lane < 32) {
            // zero cols 1032..1055
            int byte = 2064 + 2*(lane-8);
            int cc = byte >> 4, rem = (byte & 15) >> 1;
            A[r*ASTR_ + ((cc ^ key)*8) + rem] = 0;
        }
    }
    __syncthreads();

    // ---- GEMM phase (no barriers) ----
    f32x4 acc[2][4];
    #pragma unroll
    for (int m = 0; m < 2; m++)
        #pragma unroll
        for (int n = 0; n < 4; n++) acc[m][n] = (f32x4){0.f,0.f,0.f,0.f};

    const uint4* Pw = P + wv*256 + lr*4 + kg;
    int keyA = lr & 7;
    for (int kb = 0; kb < 33; kb++) {
        bf16x8 bfv[4];
        #pragma unroll
        for (int n = 0; n < 4; n++)
            bfv[n] = *(const bf16x8*)&Pw[kb*1024 + n*64];
        int ch = kb*4 + kg;
        bf16x8 af0 = *(const bf16x8*)&A[lr*ASTR_      + ((ch ^ keyA)*8)];
        bf16x8 af1 = *(const bf16x8*)&A[(16+lr)*ASTR_ + ((ch ^ keyA)*8)];
        #pragma unroll
        for (int n = 0; n < 4; n++) {
            acc[0][n] = __builtin_amdgcn_mfma_f32_16x16x32_bf16(af0, bfv[n], acc[0][n], 0, 0, 0);
            acc[1][n] = __builtin_amdgcn_mfma_f32_16x16x32_bf16(af1, bfv[n], acc[1][n], 0, 0, 0);
        }
    }

    // ---- epilogue ----
    float rsum[2][4] = {{0.f,0.f,0.f,0.f},{0.f,0.f,0.f,0.f}};
    #pragma unroll
    for (int n = 0; n < 4; n++) {
        int colg = wv*64 + n*16 + lr;
        float bgv = bg1[colg], w2v = Wg2[colg];
        #pragma unroll
        for (int m = 0; m < 2; m++)
            #pragma unroll
            for (int r = 0; r < 4; r++) {
                float gv = gelu_f(acc[m][n][r] + bgv);
                rsum[m][r] = fmaf(gv, w2v, rsum[m][r]);
            }
    }
    #pragma unroll
    for (int off = 1; off < 16; off <<= 1)
        #pragma unroll
        for (int m = 0; m < 2; m++)
            #pragma unroll
            for (int r = 0; r < 4; r++)
                rsum[m][r] += __shfl_xor(rsum[m][r], off, 64);
    if (lr == 0) {
        #pragma unroll
        for (int m = 0; m < 2; m++)
            #pragma unroll
            for (int r = 0; r < 4; r++)
                red[wv][m*16 + kg*4 + r] = rsum[m][r];
    }
    __syncthreads();
    if (tid < 32)
        out[row0 + tid] = red[0][tid] + red[1][tid] + red[2][tid] + red[3][tid] + bg2[0];
}

// ---------------------------------------------------------------------------
extern "C" void kernel_launch(void* const* d_in, const int* in_sizes, int n_in,
                              void* d_out, int out_size, void* d_ws, size_t ws_size,
                              hipStream_t stream)
{
    const float* x    = (const float*)d_in[0];
    const float* t    = (const float*)d_in[1];
    const float* Wt1  = (const float*)d_in[2];
    const float* bt1  = (const float*)d_in[3];
    const float* Wt2  = (const float*)d_in[4];
    const float* bt2  = (const float*)d_in[5];
    const float* Wpf  = (const float*)d_in[6];
    const float* bpf  = (const float*)d_in[7];
    const float* Wpb  = (const float*)d_in[8];
    const float* bpb  = (const float*)d_in[9];
    const float* Wzf  = (const float*)d_in[10];
    const float* bzf  = (const float*)d_in[11];
    const float* Whf  = (const float*)d_in[12];
    const float* bhf  = (const float*)d_in[13];
    const float* Wzb  = (const float*)d_in[14];
    const float* bzb  = (const float*)d_in[15];
    const float* Whb  = (const float*)d_in[16];
    const float* bhb  = (const float*)d_in[17];
    const float* ln_g = (const float*)d_in[18];
    const float* ln_b = (const float*)d_in[19];
    const float* tsc  = (const float*)d_in[20];
    const float* Wg1  = (const float*)d_in[21];
    const float* bg1  = (const float*)d_in[22];
    const float* Wg2  = (const float*)d_in[23];
    const float* bg2  = (const float*)d_in[24];
    float* out = (float*)d_out;

    char* p = (char*)d_ws;
    auto carve = [&](size_t bytes) -> char* {
        char* q = p; p += (bytes + 255) & ~(size_t)255; return q;
    };

    unsigned short* WzTf = (unsigned short*)carve((size_t)H_*H_*2);
    unsigned short* WhTf = (unsigned short*)carve((size_t)H_*H_*2);
    unsigned short* WzTb = (unsigned short*)carve((size_t)H_*H_*2);
    unsigned short* WhTb = (unsigned short*)carve((size_t)H_*H_*2);
    uint4*          Pg   = (uint4*)carve((size_t)33*1024*16);

    const size_t perBatch = (size_t)L_*H_*2*2
                          + (size_t)L_*H_*4*2
                          + (size_t)L_*NT_*4
                          + (size_t)CH_*H_*4*3*2;
    size_t fixedUsed = (size_t)(p - (char*)d_ws) + 64*1024;
    int NB = B_;
    while (NB > 1 && fixedUsed + (size_t)NB*perBatch > ws_size) NB >>= 1;

    unsigned short* inpF = (unsigned short*)carve((size_t)NB*L_*H_*2);
    unsigned short* inpB = (unsigned short*)carve((size_t)NB*L_*H_*2);
    unsigned int*   ABF  = (unsigned int*)carve((size_t)NB*L_*H_*4);
    unsigned int*   ABB  = (unsigned int*)carve((size_t)NB*L_*H_*4);
    float* tenc   = (float*)carve((size_t)NB*L_*NT_*4);
    float* Scar   = (float*)carve((size_t)2*NB*CH_*H_*4);
    float* Pcar   = (float*)carve((size_t)2*NB*CH_*H_*4);
    float* Hstart = (float*)carve((size_t)2*NB*CH_*H_*4);

    {
        dim3 g(H_/32, H_/32);
        kT<<<g, 256, 0, stream>>>(Wzf, WzTf, H_, H_, H_);
        kT<<<g, 256, 0, stream>>>(Whf, WhTf, H_, H_, H_);
        kT<<<g, 256, 0, stream>>>(Wzb, WzTb, H_, H_, H_);
        kT<<<g, 256, 0, stream>>>(Whb, WhTb, H_, H_, H_);
        kP<<<132, 256, 0, stream>>>(Wg1, Pg);
    }

    for (int b0 = 0; b0 < B_; b0 += NB) {
        int rows = NB * L_;
        k1_tenc_inp<<<rows/4, 256, 0, stream>>>(
            x + (size_t)b0*L_*2, t + (size_t)b0*L_,
            Wt1, bt1, Wt2, bt2, Wpf, bpf, Wpb, bpb,
            tenc, inpF, inpB);

        dim3 g3(rows/128, H_/64);
        k3_mfma<<<g3, 256, 0, stream>>>(inpF, WzTf, WhTf, bzf, bhf, ABF);
        k3_mfma<<<g3, 256, 0, stream>>>(inpB, WzTb, WhTb, bzb, bhb, ABB);

        int scanThreads = 2*NB*H_*CH_;
        k4a<<<scanThreads/256, 256, 0, stream>>>(ABF, ABB, Scar, Pcar, NB);
        k4b<<<(2*NB*H_)/256, 256, 0, stream>>>(Scar, Pcar, Hstart, NB);

        k5_fused<<<rows/32, 256, 0, stream>>>(
            ABF, ABB, Hstart, tenc, ln_g, ln_b, tsc,
            Pg, bg1, Wg2, bg2, out + (size_t)b0*L_, NB);
    }
}

// Round 6
// 314.900 us; speedup vs baseline: 1.7739x; 1.7739x over previous
//
#include <hip/hip_runtime.h>
#include <hip/hip_bf16.h>
#include <math.h>

#define B_    16
#define L_    2048
#define H_    512
#define NT_   8
#define OUT_  1032
#define KPAD_ 1056
#define HEAD_ 256
#define CH_   16
#define CL_   (L_/CH_)   // 128

// k5 A-LDS geometry: 32 rows, 136 chunks of 16B (2176B row), XOR-swizzled
#define ACH_  136
#define ASTR_ (ACH_*8)   // shorts per row = 1088

typedef short bf16x8 __attribute__((ext_vector_type(8)));
typedef float f32x4  __attribute__((ext_vector_type(4)));

__device__ __forceinline__ float b2f(unsigned short u) {
    union { unsigned int u32; float f; } v; v.u32 = ((unsigned int)u) << 16; return v.f;
}
__device__ __forceinline__ unsigned short f2b(float f) {
    __hip_bfloat16 h = __float2bfloat16(f);
    return *reinterpret_cast<unsigned short*>(&h);
}
__device__ __forceinline__ float sigmoid_f(float x) {
    return 1.f / (1.f + exp2f(-1.44269504f * x));
}
__device__ __forceinline__ float tanh_f(float x) {
    float e = exp2f(2.88539008f * x);
    return 1.f - 2.f / (e + 1.f);
}
__device__ __forceinline__ float gelu_f(float g) {
    float u  = 0.70710678118654752f * g;
    float ax = fabsf(u);
    float t  = 1.f / (1.f + 0.3275911f * ax);
    float poly = ((((1.061405429f*t - 1.453152027f)*t + 1.421413741f)*t
                   - 0.284496736f)*t + 0.254829592f)*t;
    float e  = exp2f(-1.44269504f * ax * ax);
    float er = 1.f - poly * e;
    er = (u < 0.f) ? -er : er;
    return 0.5f * g * (1.f + er);
}

// ---------------------------------------------------------------------------
// kT: transpose + f32->bf16. in f32 [R][C] -> out bf16 [C][RP], zero r>=R.
// ---------------------------------------------------------------------------
__global__ __launch_bounds__(256) void kT(const float* __restrict__ in,
                                          unsigned short* __restrict__ out,
                                          int R, int C, int RP)
{
    __shared__ float tile[32][33];
    int c0 = blockIdx.x * 32, r0 = blockIdx.y * 32;
    int tx = threadIdx.x & 31, ty = threadIdx.x >> 5;
    #pragma unroll
    for (int j = 0; j < 32; j += 8) {
        int r = r0 + ty + j, c = c0 + tx;
        tile[ty + j][tx] = (r < R && c < C) ? in[(size_t)r*C + c] : 0.f;
    }
    __syncthreads();
    #pragma unroll
    for (int j = 0; j < 32; j += 8) {
        int c = c0 + ty + j, r = r0 + tx;
        if (c < C && r < RP) out[(size_t)c*RP + r] = f2b(tile[tx][ty + j]);
    }
}

// ---------------------------------------------------------------------------
// kP: pack Wg1 (f32 [OUT_][256]) into MFMA B-fragment chunks:
// P[kb*1024 + c*4 + kg] = bf16 Wg1[kb*32+kg*8 .. +8][c]  (zero for k>=OUT_)
// ---------------------------------------------------------------------------
__global__ __launch_bounds__(256) void kP(const float* __restrict__ Wg1,
                                          uint4* __restrict__ P)
{
    int idx = blockIdx.x*256 + threadIdx.x;
    if (idx >= 33*1024) return;
    int kb = idx >> 10;
    int rem = idx & 1023;
    int c  = rem >> 2;
    int kg = rem & 3;
    int k0 = kb*32 + kg*8;
    unsigned short o[8];
    #pragma unroll
    for (int j = 0; j < 8; j++) {
        int k = k0 + j;
        o[j] = (k < OUT_) ? f2b(Wg1[(size_t)k*HEAD_ + c]) : (unsigned short)0;
    }
    P[idx] = *(const uint4*)o;
}

// ---------------------------------------------------------------------------
// K1: wave-per-row. t_enc MLP (all lanes redundantly; weights -> s_loads),
// then 8 cols/lane of inp = xc @ Wp + bp, uint4 stores. 4 rows per block.
// ---------------------------------------------------------------------------
__global__ __launch_bounds__(256) void k1_tenc_inp(
    const float* __restrict__ x, const float* __restrict__ t,
    const float* __restrict__ Wt1, const float* __restrict__ bt1,
    const float* __restrict__ Wt2, const float* __restrict__ bt2,
    const float* __restrict__ Wpf, const float* __restrict__ bpf,
    const float* __restrict__ Wpb, const float* __restrict__ bpb,
    float* __restrict__ t_enc,
    unsigned short* __restrict__ inp_f, unsigned short* __restrict__ inp_b)
{
    int wv = threadIdx.x >> 6, lane = threadIdx.x & 63;
    size_t row = (size_t)blockIdx.x*4 + wv;
    float tv = t[row];
    float r1[NT_], te[NT_];
    #pragma unroll
    for (int k = 0; k < NT_; k++) r1[k] = fmaxf(tv*Wt1[k] + bt1[k], 0.f);
    #pragma unroll
    for (int j = 0; j < NT_; j++) {
        float a = bt2[j];
        #pragma unroll
        for (int k = 0; k < NT_; k++) a = fmaf(r1[k], Wt2[k*NT_+j], a);
        te[j] = a;
    }
    if (lane < NT_) t_enc[row*NT_ + lane] = te[lane];
    float x0 = x[row*2+0], x1 = x[row*2+1];
    int c0 = lane*8;
    float af[8], ab[8];
    #pragma unroll
    for (int j = 0; j < 8; j++) {
        int c = c0 + j;
        af[j] = fmaf(x0, Wpf[c], fmaf(x1, Wpf[H_+c], bpf[c]));
        ab[j] = fmaf(x0, Wpb[c], fmaf(x1, Wpb[H_+c], bpb[c]));
    }
    #pragma unroll
    for (int k = 0; k < NT_; k++) {
        #pragma unroll
        for (int j = 0; j < 8; j++) {
            af[j] = fmaf(te[k], Wpf[(2+k)*H_+c0+j], af[j]);
            ab[j] = fmaf(te[k], Wpb[(2+k)*H_+c0+j], ab[j]);
        }
    }
    unsigned short of[8], ob[8];
    #pragma unroll
    for (int j = 0; j < 8; j++) { of[j] = f2b(af[j]); ob[j] = f2b(ab[j]); }
    *(uint4*)&inp_f[row*H_ + c0] = *(const uint4*)of;
    *(uint4*)&inp_b[row*H_ + c0] = *(const uint4*)ob;
}

// ---------------------------------------------------------------------------
// K3 (MFMA): ab = pack(1-sig(inp@Wz+bz), sig*tanh(inp@Wh+bh)).
// Round-4 proven structure: tile 128x64, BK=32, 80B-padded LDS rows (frag
// reads 2-way aliased = free), 32B/lane paired staging. New: XCD-chunked
// block remap (same-A col-blocks temporally adjacent on one XCD -> L2 reuse)
// + exp2 transcendentals.
// ---------------------------------------------------------------------------
__global__ __launch_bounds__(256) void k3_mfma(
    const unsigned short* __restrict__ inp,   // [M][512] bf16
    const unsigned short* __restrict__ WzT,   // [512][512] bf16, [n][k]
    const unsigned short* __restrict__ WhT,
    const float* __restrict__ bz, const float* __restrict__ bh,
    unsigned int* __restrict__ ab_out, int nwg)
{
    __shared__ __align__(16) unsigned short As[128*40];
    __shared__ __align__(16) unsigned short Zs[64*40];
    __shared__ __align__(16) unsigned short Hs[64*40];
    int tid = threadIdx.x;
    int lane = tid & 63, w = tid >> 6;
    int wm = w >> 1, wn = w & 1;

    // XCD-chunked remap: dispatch round-robins bid%8 across XCDs; give XCD c
    // the contiguous tile range [c*cpx, (c+1)*cpx). nwg % 8 == 0 always.
    int bid = blockIdx.x;
    int cpx = nwg >> 3;
    int tile = (bid & 7) * cpx + (bid >> 3);
    int row0 = (tile >> 3) * 128;
    int n0   = (tile & 7) * 64;

    f32x4 accz[4][2], acch[4][2];
    #pragma unroll
    for (int m = 0; m < 4; m++)
        #pragma unroll
        for (int n = 0; n < 2; n++) {
            accz[m][n] = (f32x4){0.f,0.f,0.f,0.f};
            acch[m][n] = (f32x4){0.f,0.f,0.f,0.f};
        }

    int ar = tid >> 1, aseg = tid & 1;
    int bu = tid & 127;
    int br = bu >> 1, bseg = bu & 1;
    const unsigned short* WT = (tid < 128) ? WzT : WhT;
    unsigned short* BS = (tid < 128) ? Zs : Hs;

    int kg = lane >> 4, lr = lane & 15;

    for (int k0 = 0; k0 < H_; k0 += 32) {
        const uint4* ga = (const uint4*)&inp[(size_t)(row0+ar)*H_ + k0 + aseg*16];
        uint4 va0 = ga[0], va1 = ga[1];
        const uint4* gb = (const uint4*)&WT[(size_t)(n0+br)*H_ + k0 + bseg*16];
        uint4 vb0 = gb[0], vb1 = gb[1];
        __syncthreads();
        *(uint4*)&As[ar*40 + aseg*16]     = va0;
        *(uint4*)&As[ar*40 + aseg*16 + 8] = va1;
        *(uint4*)&BS[br*40 + bseg*16]     = vb0;
        *(uint4*)&BS[br*40 + bseg*16 + 8] = vb1;
        __syncthreads();
        bf16x8 af[4], zf[2], hf[2];
        #pragma unroll
        for (int m = 0; m < 4; m++)
            af[m] = *(const bf16x8*)&As[(wm*64 + m*16 + lr)*40 + kg*8];
        #pragma unroll
        for (int n = 0; n < 2; n++) {
            zf[n] = *(const bf16x8*)&Zs[(wn*32 + n*16 + lr)*40 + kg*8];
            hf[n] = *(const bf16x8*)&Hs[(wn*32 + n*16 + lr)*40 + kg*8];
        }
        #pragma unroll
        for (int m = 0; m < 4; m++)
            #pragma unroll
            for (int n = 0; n < 2; n++) {
                accz[m][n] = __builtin_amdgcn_mfma_f32_16x16x32_bf16(af[m], zf[n], accz[m][n], 0, 0, 0);
                acch[m][n] = __builtin_amdgcn_mfma_f32_16x16x32_bf16(af[m], hf[n], acch[m][n], 0, 0, 0);
            }
    }

    #pragma unroll
    for (int m = 0; m < 4; m++)
        #pragma unroll
        for (int n = 0; n < 2; n++) {
            int colg = n0 + wn*32 + n*16 + lr;
            float bzv = bz[colg], bhv = bh[colg];
            #pragma unroll
            for (int r = 0; r < 4; r++) {
                int rowg = row0 + wm*64 + m*16 + kg*4 + r;
                float zg = sigmoid_f(accz[m][n][r] + bzv);
                float a = 1.f - zg;
                float b = zg * tanh_f(acch[m][n][r] + bhv);
                ab_out[(size_t)rowg*H_ + colg] =
                    (unsigned int)f2b(a) | ((unsigned int)f2b(b) << 16);
            }
        }
}

// ---------------------------------------------------------------------------
// K4a: chunked scan pass A. In-place: read gate pack(a,b), write pack(S,PP).
// ---------------------------------------------------------------------------
__global__ __launch_bounds__(256) void k4a(
    unsigned int* __restrict__ ABF, unsigned int* __restrict__ ABB,
    float* __restrict__ Scar, float* __restrict__ Pcar, int nb)
{
    int g = blockIdx.x*256 + threadIdx.x;
    int col   = g & (H_-1);
    int chunk = (g >> 9) & (CH_-1);
    int rest  = g >> 13;
    int bb    = rest % nb;
    int dir   = rest / nb;
    unsigned int* AB = dir ? ABB : ABF;
    size_t base = (size_t)bb * L_ * H_ + col;
    float h = 0.f, pp = 1.f;
    if (dir == 0) {
        int lo = chunk * CL_;
        for (int p = 0; p < CL_; p += 8) {
            unsigned int v[8];
            #pragma unroll
            for (int j = 0; j < 8; j++) v[j] = AB[base + (size_t)(lo+p+j)*H_];
            #pragma unroll
            for (int j = 0; j < 8; j++) {
                size_t idx = base + (size_t)(lo+p+j)*H_;
                float av = b2f((unsigned short)(v[j] & 0xffffu));
                float bv = b2f((unsigned short)(v[j] >> 16));
                AB[idx] = (unsigned int)f2b(h) | ((unsigned int)f2b(pp) << 16);
                h = fmaf(av, h, bv);
                pp *= av;
            }
        }
    } else {
        int hi = chunk * CL_ + CL_ - 1;
        for (int p = 0; p < CL_; p += 8) {
            unsigned int v[8];
            #pragma unroll
            for (int j = 0; j < 8; j++) v[j] = AB[base + (size_t)(hi-p-j)*H_];
            #pragma unroll
            for (int j = 0; j < 8; j++) {
                size_t idx = base + (size_t)(hi-p-j)*H_;
                float av = b2f((unsigned short)(v[j] & 0xffffu));
                float bv = b2f((unsigned short)(v[j] >> 16));
                AB[idx] = (unsigned int)f2b(h) | ((unsigned int)f2b(pp) << 16);
                h = fmaf(av, h, bv);
                pp *= av;
            }
        }
    }
    int ci = ((dir*nb + bb)*CH_ + chunk)*H_ + col;
    Scar[ci] = h; Pcar[ci] = pp;
}

// K4b: chain carries across chunks.
__global__ __launch_bounds__(256) void k4b(
    const float* __restrict__ Scar, const float* __restrict__ Pcar,
    float* __restrict__ Hstart, int nb)
{
    int g = blockIdx.x*256 + threadIdx.x;
    int col  = g & (H_-1);
    int rest = g >> 9;
    int bb   = rest % nb;
    int dir  = rest / nb;
    int baseci = (dir*nb + bb)*CH_;
    float h = 0.f;
    if (dir == 0) {
        for (int c = 0; c < CH_; c++) {
            int ci = (baseci + c)*H_ + col;
            Hstart[ci] = h;
            h = Scar[ci] + Pcar[ci]*h;
        }
    } else {
        for (int c = CH_-1; c >= 0; c--) {
            int ci = (baseci + c)*H_ + col;
            Hstart[ci] = h;
            h = Scar[ci] + Pcar[ci]*h;
        }
    }
}

// ---------------------------------------------------------------------------
// K5 fused: (h = S + PP*h0) + LN(1032) + affine + time_scale -> XOR-swizzled
// LDS A [32][136 chunks], then barrier-free head GEMM with fragment-packed
// B loads (fully coalesced), gelu*Wg2 + shfl row-reduce epilogue.
// ---------------------------------------------------------------------------
__global__ __launch_bounds__(256) void k5_fused(
    const unsigned int* __restrict__ SPF, const unsigned int* __restrict__ SPB,
    const float* __restrict__ Hstart,
    const float* __restrict__ tenc,
    const float* __restrict__ ln_g, const float* __restrict__ ln_b,
    const float* __restrict__ tsp,
    const uint4* __restrict__ P,              // packed Wg1 fragments
    const float* __restrict__ bg1, const float* __restrict__ Wg2,
    const float* __restrict__ bg2,
    float* __restrict__ out, int nb)
{
    __shared__ __align__(16) unsigned short A[32*ASTR_];   // 68KB
    __shared__ float red[4][32];
    int tid = threadIdx.x, lane = tid & 63, wv = tid >> 6;
    int kg = lane >> 4, lr = lane & 15;
    int row0 = blockIdx.x * 32;
    float ts = tsp[0];

    int bb    = row0 >> 11;          // / L_
    int chunk = (row0 & (L_-1)) >> 7;
    int cif = ((bb)*CH_ + chunk)*H_;
    int cib = ((nb + bb)*CH_ + chunk)*H_;
    int c0 = lane*8;
    float4 hfa = *(const float4*)&Hstart[cif + c0];
    float4 hfb = *(const float4*)&Hstart[cif + c0 + 4];
    float4 hba = *(const float4*)&Hstart[cib + c0];
    float4 hbb = *(const float4*)&Hstart[cib + c0 + 4];
    float h0f[8] = {hfa.x,hfa.y,hfa.z,hfa.w,hfb.x,hfb.y,hfb.z,hfb.w};
    float h0b[8] = {hba.x,hba.y,hba.z,hba.w,hbb.x,hbb.y,hbb.z,hbb.w};

    float gf[8], bf_[8], gb_[8], bb_[8];
    #pragma unroll
    for (int j = 0; j < 8; j++) {
        gf[j]  = ln_g[c0+j];     bf_[j] = ln_b[c0+j];
        gb_[j] = ln_g[H_+c0+j];  bb_[j] = ln_b[H_+c0+j];
    }
    float gt = 0.f, bt = 0.f;
    if (lane < NT_) { gt = ln_g[2*H_+lane]; bt = ln_b[2*H_+lane]; }

    #pragma unroll
    for (int i = 0; i < 8; i++) {
        int r = wv*8 + i;
        size_t row = (size_t)row0 + r;
        const uint4* pf = (const uint4*)&SPF[row*H_ + c0];
        uint4 f0 = pf[0], f1 = pf[1];
        const uint4* pb = (const uint4*)&SPB[row*H_ + c0];
        uint4 b0 = pb[0], b1 = pb[1];
        unsigned int fwv[8] = {f0.x,f0.y,f0.z,f0.w,f1.x,f1.y,f1.z,f1.w};
        unsigned int bwv[8] = {b0.x,b0.y,b0.z,b0.w,b1.x,b1.y,b1.z,b1.w};
        float fv[8], bv[8];
        float S = 0.f, Q = 0.f;
        #pragma unroll
        for (int j = 0; j < 8; j++) {
            fv[j] = fmaf(b2f((unsigned short)(fwv[j] >> 16)), h0f[j],
                         b2f((unsigned short)(fwv[j] & 0xffffu)));
            S += fv[j]; Q += fv[j]*fv[j];
            bv[j] = fmaf(b2f((unsigned short)(bwv[j] >> 16)), h0b[j],
                         b2f((unsigned short)(bwv[j] & 0xffffu)));
            S += bv[j]; Q += bv[j]*bv[j];
        }
        float tv = 0.f;
        if (lane < NT_) { tv = tenc[row*NT_ + lane]; S += tv; Q += tv*tv; }
        #pragma unroll
        for (int off = 32; off > 0; off >>= 1) {
            S += __shfl_xor(S, off, 64);
            Q += __shfl_xor(Q, off, 64);
        }
        float mu = S * (1.f/1032.f);
        float rs = rsqrtf(Q * (1.f/1032.f) - mu*mu + 1e-5f);
        int key = r & 7;
        unsigned short o[8];
        #pragma unroll
        for (int j = 0; j < 8; j++) o[j] = f2b((fv[j]-mu)*rs*gf[j] + bf_[j]);
        *(uint4*)&A[r*ASTR_ + ((lane ^ key)*8)] = *(const uint4*)o;
        #pragma unroll
        for (int j = 0; j < 8; j++) o[j] = f2b((bv[j]-mu)*rs*gb_[j] + bb_[j]);
        *(uint4*)&A[r*ASTR_ + (((64+lane) ^ key)*8)] = *(const uint4*)o;
        if (lane < NT_) {
            A[r*ASTR_ + ((128 ^ key)*8) + lane] =
                f2b(((tv-mu)*rs*gt + bt) * ts);
        } else if (lane < 32) {
            int byte = 2064 + 2*(lane-8);
            int cc = byte >> 4, rem = (byte & 15) >> 1;
            A[r*ASTR_ + ((cc ^ key)*8) + rem] = 0;
        }
    }
    __syncthreads();

    // ---- GEMM phase (no barriers) ----
    f32x4 acc[2][4];
    #pragma unroll
    for (int m = 0; m < 2; m++)
        #pragma unroll
        for (int n = 0; n < 4; n++) acc[m][n] = (f32x4){0.f,0.f,0.f,0.f};

    const uint4* Pw = P + wv*256 + lr*4 + kg;
    int keyA = lr & 7;
    for (int kb = 0; kb < 33; kb++) {
        bf16x8 bfv[4];
        #pragma unroll
        for (int n = 0; n < 4; n++)
            bfv[n] = *(const bf16x8*)&Pw[kb*1024 + n*64];
        int ch = kb*4 + kg;
        bf16x8 af0 = *(const bf16x8*)&A[lr*ASTR_      + ((ch ^ keyA)*8)];
        bf16x8 af1 = *(const bf16x8*)&A[(16+lr)*ASTR_ + ((ch ^ keyA)*8)];
        #pragma unroll
        for (int n = 0; n < 4; n++) {
            acc[0][n] = __builtin_amdgcn_mfma_f32_16x16x32_bf16(af0, bfv[n], acc[0][n], 0, 0, 0);
            acc[1][n] = __builtin_amdgcn_mfma_f32_16x16x32_bf16(af1, bfv[n], acc[1][n], 0, 0, 0);
        }
    }

    // ---- epilogue ----
    float rsum[2][4] = {{0.f,0.f,0.f,0.f},{0.f,0.f,0.f,0.f}};
    #pragma unroll
    for (int n = 0; n < 4; n++) {
        int colg = wv*64 + n*16 + lr;
        float bgv = bg1[colg], w2v = Wg2[colg];
        #pragma unroll
        for (int m = 0; m < 2; m++)
            #pragma unroll
            for (int r = 0; r < 4; r++) {
                float gv = gelu_f(acc[m][n][r] + bgv);
                rsum[m][r] = fmaf(gv, w2v, rsum[m][r]);
            }
    }
    #pragma unroll
    for (int off = 1; off < 16; off <<= 1)
        #pragma unroll
        for (int m = 0; m < 2; m++)
            #pragma unroll
            for (int r = 0; r < 4; r++)
                rsum[m][r] += __shfl_xor(rsum[m][r], off, 64);
    if (lr == 0) {
        #pragma unroll
        for (int m = 0; m < 2; m++)
            #pragma unroll
            for (int r = 0; r < 4; r++)
                red[wv][m*16 + kg*4 + r] = rsum[m][r];
    }
    __syncthreads();
    if (tid < 32)
        out[row0 + tid] = red[0][tid] + red[1][tid] + red[2][tid] + red[3][tid] + bg2[0];
}

// ---------------------------------------------------------------------------
extern "C" void kernel_launch(void* const* d_in, const int* in_sizes, int n_in,
                              void* d_out, int out_size, void* d_ws, size_t ws_size,
                              hipStream_t stream)
{
    const float* x    = (const float*)d_in[0];
    const float* t    = (const float*)d_in[1];
    const float* Wt1  = (const float*)d_in[2];
    const float* bt1  = (const float*)d_in[3];
    const float* Wt2  = (const float*)d_in[4];
    const float* bt2  = (const float*)d_in[5];
    const float* Wpf  = (const float*)d_in[6];
    const float* bpf  = (const float*)d_in[7];
    const float* Wpb  = (const float*)d_in[8];
    const float* bpb  = (const float*)d_in[9];
    const float* Wzf  = (const float*)d_in[10];
    const float* bzf  = (const float*)d_in[11];
    const float* Whf  = (const float*)d_in[12];
    const float* bhf  = (const float*)d_in[13];
    const float* Wzb  = (const float*)d_in[14];
    const float* bzb  = (const float*)d_in[15];
    const float* Whb  = (const float*)d_in[16];
    const float* bhb  = (const float*)d_in[17];
    const float* ln_g = (const float*)d_in[18];
    const float* ln_b = (const float*)d_in[19];
    const float* tsc  = (const float*)d_in[20];
    const float* Wg1  = (const float*)d_in[21];
    const float* bg1  = (const float*)d_in[22];
    const float* Wg2  = (const float*)d_in[23];
    const float* bg2  = (const float*)d_in[24];
    float* out = (float*)d_out;

    char* p = (char*)d_ws;
    auto carve = [&](size_t bytes) -> char* {
        char* q = p; p += (bytes + 255) & ~(size_t)255; return q;
    };

    unsigned short* WzTf = (unsigned short*)carve((size_t)H_*H_*2);
    unsigned short* WhTf = (unsigned short*)carve((size_t)H_*H_*2);
    unsigned short* WzTb = (unsigned short*)carve((size_t)H_*H_*2);
    unsigned short* WhTb = (unsigned short*)carve((size_t)H_*H_*2);
    uint4*          Pg   = (uint4*)carve((size_t)33*1024*16);

    const size_t perBatch = (size_t)L_*H_*2*2
                          + (size_t)L_*H_*4*2
                          + (size_t)L_*NT_*4
                          + (size_t)CH_*H_*4*3*2;
    size_t fixedUsed = (size_t)(p - (char*)d_ws) + 64*1024;
    int NB = B_;
    while (NB > 1 && fixedUsed + (size_t)NB*perBatch > ws_size) NB >>= 1;

    unsigned short* inpF = (unsigned short*)carve((size_t)NB*L_*H_*2);
    unsigned short* inpB = (unsigned short*)carve((size_t)NB*L_*H_*2);
    unsigned int*   ABF  = (unsigned int*)carve((size_t)NB*L_*H_*4);
    unsigned int*   ABB  = (unsigned int*)carve((size_t)NB*L_*H_*4);
    float* tenc   = (float*)carve((size_t)NB*L_*NT_*4);
    float* Scar   = (float*)carve((size_t)2*NB*CH_*H_*4);
    float* Pcar   = (float*)carve((size_t)2*NB*CH_*H_*4);
    float* Hstart = (float*)carve((size_t)2*NB*CH_*H_*4);

    {
        dim3 g(H_/32, H_/32);
        kT<<<g, 256, 0, stream>>>(Wzf, WzTf, H_, H_, H_);
        kT<<<g, 256, 0, stream>>>(Whf, WhTf, H_, H_, H_);
        kT<<<g, 256, 0, stream>>>(Wzb, WzTb, H_, H_, H_);
        kT<<<g, 256, 0, stream>>>(Whb, WhTb, H_, H_, H_);
        kP<<<132, 256, 0, stream>>>(Wg1, Pg);
    }

    for (int b0 = 0; b0 < B_; b0 += NB) {
        int rows = NB * L_;
        k1_tenc_inp<<<rows/4, 256, 0, stream>>>(
            x + (size_t)b0*L_*2, t + (size_t)b0*L_,
            Wt1, bt1, Wt2, bt2, Wpf, bpf, Wpb, bpb,
            tenc, inpF, inpB);

        int nwg3 = (rows/128) * (H_/64);
        k3_mfma<<<nwg3, 256, 0, stream>>>(inpF, WzTf, WhTf, bzf, bhf, ABF, nwg3);
        k3_mfma<<<nwg3, 256, 0, stream>>>(inpB, WzTb, WhTb, bzb, bhb, ABB, nwg3);

        int scanThreads = 2*NB*H_*CH_;
        k4a<<<scanThreads/256, 256, 0, stream>>>(ABF, ABB, Scar, Pcar, NB);
        k4b<<<(2*NB*H_)/256, 256, 0, stream>>>(Scar, Pcar, Hstart, NB);

        k5_fused<<<rows/32, 256, 0, stream>>>(
            ABF, ABB, Hstart, tenc, ln_g, ln_b, tsc,
            Pg, bg1, Wg2, bg2, out + (size_t)b0*L_, NB);
    }
}